// Round 8
// baseline (115.503 us; speedup 1.0000x reference)
//
#include <hip/hip_runtime.h>
#include <hip/hip_bf16.h>

typedef short short8 __attribute__((ext_vector_type(8)));
typedef float f32x4 __attribute__((ext_vector_type(4)));

#define BARRIER_TAG 0x5EEDF00Du

__device__ __forceinline__ float bf2f(unsigned short v) {
    unsigned int u = ((unsigned int)v) << 16;
    float f;
    __builtin_memcpy(&f, &u, 4);
    return f;
}

__device__ __forceinline__ unsigned short f2bf(float f) {
    unsigned int u;
    __builtin_memcpy(&u, &f, 4);
    u += 0x7fffu + ((u >> 16) & 1u);   // RNE
    return (unsigned short)(u >> 16);
}

__device__ __forceinline__ unsigned int pack2(float a, float b) {
    return (unsigned int)f2bf(a) | ((unsigned int)f2bf(b) << 16);
}

// truncation pack (1 v_perm_b32): a -> low16, b -> high16
__device__ __forceinline__ unsigned int pack_trunc(float a, float b) {
    unsigned int ua, ub;
    __builtin_memcpy(&ua, &a, 4);
    __builtin_memcpy(&ub, &b, 4);
    return __builtin_amdgcn_perm(ub, ua, 0x07060302u);
}

// split a,b into bf16 hi + bf16 lo packed pairs (hi+lo ~ fp32-accurate)
__device__ __forceinline__ void split2(float a, float b,
                                       unsigned int& hi, unsigned int& lo) {
    unsigned short ah = f2bf(a), bh = f2bf(b);
    float al = a - bf2f(ah), bl = b - bf2f(bh);
    hi = (unsigned int)ah | ((unsigned int)bh << 16);
    lo = (unsigned int)f2bf(al) | ((unsigned int)f2bf(bl) << 16);
}

// Runtime dtype dispatch (proven fp32 on this harness, kept for robustness).
__device__ __forceinline__ float loadv(const void* p, int idx, bool is_fp32) {
    return is_fp32 ? ((const float*)p)[idx] : bf2f(((const unsigned short*)p)[idx]);
}

// In-register C-layout -> A-layout permutation for P (verified 3-cycle:
// swap(lane5,reg1) then swap(lane4,reg1)).
__device__ __forceinline__ short8 p_to_afrag(unsigned int pk0, unsigned int pk1,
                                             unsigned int pk2, unsigned int pk3,
                                             int lane) {
    {
        unsigned int s0 = __shfl_xor(pk0, 32), s2 = __shfl_xor(pk2, 32);
        bool hi = (lane & 32) != 0;
        unsigned int n0 = hi ? s2 : pk0;
        unsigned int n2 = hi ? pk2 : s0;
        pk0 = n0; pk2 = n2;
        unsigned int s1 = __shfl_xor(pk1, 32), s3 = __shfl_xor(pk3, 32);
        unsigned int n1 = hi ? s3 : pk1;
        unsigned int n3 = hi ? pk3 : s1;
        pk1 = n1; pk3 = n3;
    }
    {
        unsigned int s0 = __shfl_xor(pk0, 16), s2 = __shfl_xor(pk2, 16);
        bool hi = (lane & 16) != 0;
        unsigned int n0 = hi ? s2 : pk0;
        unsigned int n2 = hi ? pk2 : s0;
        pk0 = n0; pk2 = n2;
        unsigned int s1 = __shfl_xor(pk1, 16), s3 = __shfl_xor(pk3, 16);
        unsigned int n1 = hi ? s3 : pk1;
        unsigned int n3 = hi ? pk3 : s1;
        pk1 = n1; pk3 = n3;
    }
    union { unsigned int u[4]; short8 s8; } pf;
    pf.u[0] = pk0; pf.u[1] = pk1; pf.u[2] = pk2; pf.u[3] = pk3;
    return pf.s8;
}

// ---------------------------------------------------------------------------
// Fused kernel: phase A = projections (split-bf16 MFMA GEMM, W in LDS),
// software all-arrive grid barrier (agent-scope atomics, slots in d_ws,
// poison 0xAAAAAAAA != TAG guarantees reset), phase B = flash attention
// (no-max exp, LDS-free barrier-free K-loop) + fused output projection.
// Grid: 256 WGs x 1024 thr (16 waves).  1 WG/CU -> co-residency guaranteed.
// ---------------------------------------------------------------------------
__global__ __launch_bounds__(1024, 4) void fused_kernel(
    const void* __restrict__ x,
    const void* __restrict__ Wf, const void* __restrict__ bfv,
    const void* __restrict__ Wg, const void* __restrict__ bgv,
    const void* __restrict__ Wh, const void* __restrict__ bhv,
    const void* __restrict__ Wo, const void* __restrict__ bo,
    const void* __restrict__ gamma_p,
    unsigned short* __restrict__ F, unsigned short* __restrict__ G,
    unsigned short* __restrict__ Ht, unsigned int* __restrict__ slots,
    void* __restrict__ out) {
    __shared__ unsigned int WTh[3 * 32 * 36];   // phase A: W hi pairs
    __shared__ unsigned int WTl[3 * 32 * 36];   // phase A: W lo pairs
    __shared__ float bL[96];
    __shared__ float O_lds[16][32][32];         // phase B
    __shared__ float l_lds[16][32];
    __shared__ float Om[32][33];
    __shared__ float lmg[32];
    __shared__ float WoL[32][64];
    __shared__ float boL[64];
    __shared__ int dflag;

    int tid = threadIdx.x;
    int bx = blockIdx.x;            // 0..255
    // dtype sniff (wave 0)
    if (tid < 64) {
        unsigned int w = ((const unsigned int*)x)[tid];
        unsigned int e = (w >> 7) & 0xFFu;
        unsigned long long m = __ballot(e > 140u);
        if (tid == 0) dflag = (__popcll(m) >= 8) ? 1 : 0;
    }
    int wave = tid >> 6;
    int lane = tid & 63;
    int Q = lane >> 4, l15 = lane & 15;

    // ---- phase A staging: W (split) + Wo/bo for phase B ----
    {
        const void* Ws[3] = {Wf, Wg, Wh};
        __syncthreads();                 // dflag ready
        bool fp32 = dflag != 0;
        for (int i = tid; i < 3072; i += 1024) {
            int m = i >> 10;
            int r = i & 1023;
            int p = r >> 5, n = r & 31;
            float e0 = loadv(Ws[m], (2 * p) * 32 + n, fp32);
            float e1 = loadv(Ws[m], (2 * p + 1) * 32 + n, fp32);
            unsigned int hi, lo;
            split2(e0, e1, hi, lo);
            WTh[(m * 32 + n) * 36 + p] = hi;
            WTl[(m * 32 + n) * 36 + p] = lo;
        }
        if (tid < 96) {
            const void* bsrc = (tid < 32) ? bfv : (tid < 64) ? bgv : bhv;
            bL[tid] = loadv(bsrc, tid & 31, fp32);
        }
        for (int i = tid; i < 2048; i += 1024) WoL[i >> 6][i & 63] = loadv(Wo, i, fp32);
        if (tid < 64) boL[tid] = loadv(bo, tid, fp32);
    }
    __syncthreads();
    bool fp32 = dflag != 0;

    // ---- phase A compute: 12 units = 2 row-tiles x {3 matrices x 2 col-halves}
    if (wave < 12) {
        int tile = wave & 1;
        int mcb = wave >> 1;
        int m = mcb >> 1, cb = mcb & 1;
        int row0 = (bx << 5) + (tile << 4);

        short8 a0h, a0l, a1h, a1l;
        {
            int base = (row0 + l15) * 64 + Q * 8;
            union { unsigned int u[4]; short8 s8; } A0h, A0l, A1h, A1l;
            if (fp32) {
                const float* xf = (const float*)x;
                f32x4 v0 = *(const f32x4*)(xf + base);
                f32x4 v1 = *(const f32x4*)(xf + base + 4);
                f32x4 w0 = *(const f32x4*)(xf + base + 32);
                f32x4 w1 = *(const f32x4*)(xf + base + 36);
                split2(v0[0], v0[1], A0h.u[0], A0l.u[0]);
                split2(v0[2], v0[3], A0h.u[1], A0l.u[1]);
                split2(v1[0], v1[1], A0h.u[2], A0l.u[2]);
                split2(v1[2], v1[3], A0h.u[3], A0l.u[3]);
                split2(w0[0], w0[1], A1h.u[0], A1l.u[0]);
                split2(w0[2], w0[3], A1h.u[1], A1l.u[1]);
                split2(w1[0], w1[1], A1h.u[2], A1l.u[2]);
                split2(w1[2], w1[3], A1h.u[3], A1l.u[3]);
            } else {
                const unsigned short* xb = (const unsigned short*)x;
                A0h.s8 = *(const short8*)(xb + base);
                A1h.s8 = *(const short8*)(xb + base + 32);
                A0l.u[0] = A0l.u[1] = A0l.u[2] = A0l.u[3] = 0;
                A1l = A0l;
            }
            a0h = A0h.s8; a0l = A0l.s8; a1h = A1h.s8; a1l = A1l.s8;
        }
        int rowbase = (m * 32 + cb * 16 + l15) * 36;
        union { uint4 v; short8 s8; } B0h, B0l, B1h, B1l;
        B0h.v = *(const uint4*)&WTh[rowbase + Q * 4];
        B1h.v = *(const uint4*)&WTh[rowbase + 16 + Q * 4];
        B0l.v = *(const uint4*)&WTl[rowbase + Q * 4];
        B1l.v = *(const uint4*)&WTl[rowbase + 16 + Q * 4];
        f32x4 z = {0.f, 0.f, 0.f, 0.f};
        f32x4 acc = __builtin_amdgcn_mfma_f32_16x16x32_bf16(a0h, B0h.s8, z, 0, 0, 0);
        acc = __builtin_amdgcn_mfma_f32_16x16x32_bf16(a0h, B0l.s8, acc, 0, 0, 0);
        acc = __builtin_amdgcn_mfma_f32_16x16x32_bf16(a0l, B0h.s8, acc, 0, 0, 0);
        acc = __builtin_amdgcn_mfma_f32_16x16x32_bf16(a1h, B1h.s8, acc, 0, 0, 0);
        acc = __builtin_amdgcn_mfma_f32_16x16x32_bf16(a1h, B1l.s8, acc, 0, 0, 0);
        acc = __builtin_amdgcn_mfma_f32_16x16x32_bf16(a1l, B1h.s8, acc, 0, 0, 0);
        float bias = bL[m * 32 + cb * 16 + l15];
        if (m < 2) {
            unsigned short* dst = (m == 0) ? F : G;
#pragma unroll
            for (int r = 0; r < 4; r++)
                dst[(row0 + Q * 4 + r) * 32 + cb * 16 + l15] = f2bf(acc[r] + bias);
        } else {
            int b = row0 >> 12;
            int n0 = (row0 & 4095) + Q * 4;
            uint2 pk;
            pk.x = pack2(acc[0] + bias, acc[1] + bias);
            pk.y = pack2(acc[2] + bias, acc[3] + bias);
            *(uint2*)(Ht + b * 131072 + (cb * 16 + l15) * 4096 + n0) = pk;
        }
    }
    __syncthreads();     // all phase-A stores drained (vmcnt 0 per thread)

    // ---- software grid barrier (agent-scope; slots pre-poisoned != TAG) ----
    if (tid == 0)
        __hip_atomic_store(&slots[bx], BARRIER_TAG, __ATOMIC_RELEASE,
                           __HIP_MEMORY_SCOPE_AGENT);
    if (tid < 256) {
        int guard = 0;
        while (__hip_atomic_load(&slots[tid], __ATOMIC_ACQUIRE,
                                 __HIP_MEMORY_SCOPE_AGENT) != BARRIER_TAG &&
               guard < (1 << 20))
            ++guard;
    }
    __syncthreads();

    // ---- phase B: flash attention, 32 queries/WG, K-split 16 ----
    int b = bx >> 7;
    int q0 = (bx & 127) << 5;
    const unsigned short* Fb = F + (b << 17);
    const unsigned short* Gb = G + (b << 17);
    const unsigned short* Htb = Ht + (b << 17);

    short8 g0 = *(const short8*)(Gb + ((q0 + l15) << 5) + (Q << 3));
    short8 g1 = *(const short8*)(Gb + ((q0 + 16 + l15) << 5) + (Q << 3));

    f32x4 O00 = {0.f, 0.f, 0.f, 0.f}, O01 = O00, O10 = O00, O11 = O00;
    float ls0 = 0.f, ls1 = 0.f;

    int k_begin = wave << 8;        // 256 keys per wave
#pragma unroll 2
    for (int it = 0; it < 8; ++it) {
        int kk = k_begin + (it << 5);
        short8 af0 = *(const short8*)(Fb + ((kk + l15) << 5) + (Q << 3));
        short8 af1 = *(const short8*)(Fb + ((kk + 16 + l15) << 5) + (Q << 3));
        short8 bh0 = *(const short8*)(Htb + (l15 << 12) + kk + (Q << 3));
        short8 bh1 = *(const short8*)(Htb + ((16 + l15) << 12) + kk + (Q << 3));

        f32x4 z = {0.f, 0.f, 0.f, 0.f};
        f32x4 c00 = __builtin_amdgcn_mfma_f32_16x16x32_bf16(af0, g0, z, 0, 0, 0);
        f32x4 c01 = __builtin_amdgcn_mfma_f32_16x16x32_bf16(af1, g0, z, 0, 0, 0);
        f32x4 c10 = __builtin_amdgcn_mfma_f32_16x16x32_bf16(af0, g1, z, 0, 0, 0);
        f32x4 c11 = __builtin_amdgcn_mfma_f32_16x16x32_bf16(af1, g1, z, 0, 0, 0);

        float e00[4], e01[4], e10[4], e11[4];
#pragma unroll
        for (int r = 0; r < 4; r++) {
            e00[r] = __expf(c00[r]); e01[r] = __expf(c01[r]);
            e10[r] = __expf(c10[r]); e11[r] = __expf(c11[r]);
            ls0 += e00[r] + e01[r];
            ls1 += e10[r] + e11[r];
        }

        short8 pf0 = p_to_afrag(pack_trunc(e00[0], e00[1]), pack_trunc(e00[2], e00[3]),
                                pack_trunc(e01[0], e01[1]), pack_trunc(e01[2], e01[3]),
                                lane);
        short8 pf1 = p_to_afrag(pack_trunc(e10[0], e10[1]), pack_trunc(e10[2], e10[3]),
                                pack_trunc(e11[0], e11[1]), pack_trunc(e11[2], e11[3]),
                                lane);

        O00 = __builtin_amdgcn_mfma_f32_16x16x32_bf16(pf0, bh0, O00, 0, 0, 0);
        O01 = __builtin_amdgcn_mfma_f32_16x16x32_bf16(pf0, bh1, O01, 0, 0, 0);
        O10 = __builtin_amdgcn_mfma_f32_16x16x32_bf16(pf1, bh0, O10, 0, 0, 0);
        O11 = __builtin_amdgcn_mfma_f32_16x16x32_bf16(pf1, bh1, O11, 0, 0, 0);
    }

    ls0 += __shfl_xor(ls0, 16); ls0 += __shfl_xor(ls0, 32);
    ls1 += __shfl_xor(ls1, 16); ls1 += __shfl_xor(ls1, 32);
    if (Q == 0) {
        l_lds[wave][l15] = ls0;
        l_lds[wave][16 + l15] = ls1;
    }
#pragma unroll
    for (int r = 0; r < 4; r++) {
        O_lds[wave][(Q << 2) | r][l15]             = O00[r];
        O_lds[wave][(Q << 2) | r][16 + l15]        = O01[r];
        O_lds[wave][16 + ((Q << 2) | r)][l15]      = O10[r];
        O_lds[wave][16 + ((Q << 2) | r)][16 + l15] = O11[r];
    }
    __syncthreads();

    if (tid < 32) {
        float s = 0.f;
#pragma unroll
        for (int w = 0; w < 16; w++) s += l_lds[w][tid];
        lmg[tid] = 1.0f / s;
    }
    {
        int q = tid >> 5, c = tid & 31;
        float s = 0.f;
#pragma unroll
        for (int w = 0; w < 16; w++) s += O_lds[w][q][c];
        Om[q][c] = s;
    }
    __syncthreads();

    int q = tid >> 5;
    int ch = (tid & 31) << 1;
    float a0 = 0.f, a1 = 0.f;
#pragma unroll
    for (int c = 0; c < 32; c++) {
        float ob = Om[q][c];
        a0 += ob * WoL[c][ch];
        a1 += ob * WoL[c][ch + 1];
    }
    float inv = lmg[q];
    float gam = loadv(gamma_p, 0, fp32);
    int gq = q0 + q;
    int obase = (((b << 12) + gq) << 6) + ch;
    if (fp32) {
        float2 xv = *(const float2*)((const float*)x + obase);
        float2 ov;
        ov.x = xv.x + gam * (a0 * inv + boL[ch + 0]);
        ov.y = xv.y + gam * (a1 * inv + boL[ch + 1]);
        *(float2*)((float*)out + obase) = ov;
    } else {
        const unsigned short* xb = (const unsigned short*)x;
        unsigned short* ob16 = (unsigned short*)out;
        unsigned int pk = pack2(bf2f(xb[obase + 0]) + gam * (a0 * inv + boL[ch + 0]),
                                bf2f(xb[obase + 1]) + gam * (a1 * inv + boL[ch + 1]));
        *(unsigned int*)(ob16 + obase) = pk;
    }
}

extern "C" void kernel_launch(void* const* d_in, const int* in_sizes, int n_in,
                              void* d_out, int out_size, void* d_ws, size_t ws_size,
                              hipStream_t stream) {
    const void* x   = d_in[0];
    const void* Wf  = d_in[1];
    const void* bfv = d_in[2];
    const void* Wg  = d_in[3];
    const void* bgv = d_in[4];
    const void* Wh  = d_in[5];
    const void* bhv = d_in[6];
    const void* Wo  = d_in[7];
    const void* bo  = d_in[8];
    const void* gam = d_in[9];

    unsigned short* F  = (unsigned short*)d_ws;       // [B][N][32] bf16
    unsigned short* G  = F + 262144;                  // [B][N][32] bf16
    unsigned short* Ht = G + 262144;                  // [B][32][N] bf16
    unsigned int* slots = (unsigned int*)(Ht + 262144);  // 256 barrier slots

    fused_kernel<<<256, 1024, 0, stream>>>(x, Wf, bfv, Wg, bgv, Wh, bhv,
                                           Wo, bo, gam, F, G, Ht, slots, d_out);
}

// Round 10
// 99.330 us; speedup vs baseline: 1.1628x; 1.1628x over previous
//
#include <hip/hip_runtime.h>
#include <hip/hip_bf16.h>

typedef short short8 __attribute__((ext_vector_type(8)));
typedef float f32x4 __attribute__((ext_vector_type(4)));

#define LOG2E 1.4426950408889634f

__device__ __forceinline__ float bf2f(unsigned short v) {
    unsigned int u = ((unsigned int)v) << 16;
    float f;
    __builtin_memcpy(&f, &u, 4);
    return f;
}

__device__ __forceinline__ unsigned short f2bf(float f) {
    unsigned int u;
    __builtin_memcpy(&u, &f, 4);
    u += 0x7fffu + ((u >> 16) & 1u);   // RNE
    return (unsigned short)(u >> 16);
}

__device__ __forceinline__ unsigned int pack2(float a, float b) {
    return (unsigned int)f2bf(a) | ((unsigned int)f2bf(b) << 16);
}

// truncation pack (1 v_perm_b32): a -> low16, b -> high16
__device__ __forceinline__ unsigned int pack_trunc(float a, float b) {
    unsigned int ua, ub;
    __builtin_memcpy(&ua, &a, 4);
    __builtin_memcpy(&ub, &b, 4);
    return __builtin_amdgcn_perm(ub, ua, 0x07060302u);
}

// split a,b into bf16 hi + bf16 lo packed pairs (hi+lo ~ fp32-accurate)
__device__ __forceinline__ void split2(float a, float b,
                                       unsigned int& hi, unsigned int& lo) {
    unsigned short ah = f2bf(a), bh = f2bf(b);
    float al = a - bf2f(ah), bl = b - bf2f(bh);
    hi = (unsigned int)ah | ((unsigned int)bh << 16);
    lo = (unsigned int)f2bf(al) | ((unsigned int)f2bf(bl) << 16);
}

// Runtime dtype dispatch (proven fp32 on this harness, kept for robustness).
__device__ __forceinline__ float loadv(const void* p, int idx, bool is_fp32) {
    return is_fp32 ? ((const float*)p)[idx] : bf2f(((const unsigned short*)p)[idx]);
}
__device__ __forceinline__ bool detect_fp32(const void* x, int tid, int* flag_sh) {
    if (tid < 64) {                      // exactly wave 0
        unsigned int w = ((const unsigned int*)x)[tid];
        unsigned int e = (w >> 7) & 0xFFu;   // exponent of low u16 as bf16
        unsigned long long m = __ballot(e > 140u);
        if (tid == 0) *flag_sh = (__popcll(m) >= 8) ? 1 : 0;
    }
    __syncthreads();
    return *flag_sh != 0;
}

// In-register C-layout -> A-layout permutation for P (verified 3-cycle:
// swap(lane5,reg1) then swap(lane4,reg1)).
__device__ __forceinline__ short8 p_to_afrag(unsigned int pk0, unsigned int pk1,
                                             unsigned int pk2, unsigned int pk3,
                                             int lane) {
    {
        unsigned int s0 = __shfl_xor(pk0, 32), s2 = __shfl_xor(pk2, 32);
        bool hi = (lane & 32) != 0;
        unsigned int n0 = hi ? s2 : pk0;
        unsigned int n2 = hi ? pk2 : s0;
        pk0 = n0; pk2 = n2;
        unsigned int s1 = __shfl_xor(pk1, 32), s3 = __shfl_xor(pk3, 32);
        unsigned int n1 = hi ? s3 : pk1;
        unsigned int n3 = hi ? pk3 : s1;
        pk1 = n1; pk3 = n3;
    }
    {
        unsigned int s0 = __shfl_xor(pk0, 16), s2 = __shfl_xor(pk2, 16);
        bool hi = (lane & 16) != 0;
        unsigned int n0 = hi ? s2 : pk0;
        unsigned int n2 = hi ? pk2 : s0;
        pk0 = n0; pk2 = n2;
        unsigned int s1 = __shfl_xor(pk1, 16), s3 = __shfl_xor(pk3, 16);
        unsigned int n1 = hi ? s3 : pk1;
        unsigned int n3 = hi ? pk3 : s1;
        pk1 = n1; pk3 = n3;
    }
    union { unsigned int u[4]; short8 s8; } pf;
    pf.u[0] = pk0; pf.u[1] = pk1; pf.u[2] = pk2; pf.u[3] = pk3;
    return pf.s8;
}

// ---------------------------------------------------------------------------
// Kernel 1: projections as split-bf16 MFMA GEMM, W staged in LDS.
// G-path (Wg, bg) pre-scaled by log2(e) so attention can use exp2 directly.
// ---------------------------------------------------------------------------
__global__ __launch_bounds__(128) void proj_kernel(
    const void* __restrict__ x,
    const void* __restrict__ Wf, const void* __restrict__ bfv,
    const void* __restrict__ Wg, const void* __restrict__ bgv,
    const void* __restrict__ Wh, const void* __restrict__ bhv,
    unsigned short* __restrict__ F, unsigned short* __restrict__ G,
    unsigned short* __restrict__ Ht) {
    __shared__ unsigned int WTh[3 * 32 * 36];   // [m][n][p] packed hi pairs
    __shared__ unsigned int WTl[3 * 32 * 36];   // lo pairs
    __shared__ float bL[96];
    __shared__ int dflag;
    int tid = threadIdx.x;
    bool fp32 = detect_fp32(x, tid, &dflag);
    int lane = tid & 63, wave = tid >> 6;
    int Q = lane >> 4, l15 = lane & 15;
    int row0 = (blockIdx.x * 2 + wave) << 4;     // 16 voxel rows per wave

    const void* Ws[3] = {Wf, Wg, Wh};
    const void* bs[3] = {bfv, bgv, bhv};

    for (int i = tid; i < 3072; i += 128) {
        int m = i >> 10;
        int r = i & 1023;
        int p = r >> 5, n = r & 31;
        float sc = (m == 1) ? LOG2E : 1.0f;      // fold log2e into G path
        float e0 = loadv(Ws[m], (2 * p) * 32 + n, fp32) * sc;
        float e1 = loadv(Ws[m], (2 * p + 1) * 32 + n, fp32) * sc;
        unsigned int hi, lo;
        split2(e0, e1, hi, lo);
        WTh[(m * 32 + n) * 36 + p] = hi;
        WTl[(m * 32 + n) * 36 + p] = lo;
    }
    if (tid < 96) {
        float sc = (tid >= 32 && tid < 64) ? LOG2E : 1.0f;
        bL[tid] = loadv(bs[tid >> 5], tid & 31, fp32) * sc;
    }

    short8 a0h, a0l, a1h, a1l;
    {
        int base = (row0 + l15) * 64 + Q * 8;
        union { unsigned int u[4]; short8 s8; } A0h, A0l, A1h, A1l;
        if (fp32) {
            const float* xf = (const float*)x;
            f32x4 v0 = *(const f32x4*)(xf + base);
            f32x4 v1 = *(const f32x4*)(xf + base + 4);
            f32x4 w0 = *(const f32x4*)(xf + base + 32);
            f32x4 w1 = *(const f32x4*)(xf + base + 36);
            split2(v0[0], v0[1], A0h.u[0], A0l.u[0]);
            split2(v0[2], v0[3], A0h.u[1], A0l.u[1]);
            split2(v1[0], v1[1], A0h.u[2], A0l.u[2]);
            split2(v1[2], v1[3], A0h.u[3], A0l.u[3]);
            split2(w0[0], w0[1], A1h.u[0], A1l.u[0]);
            split2(w0[2], w0[3], A1h.u[1], A1l.u[1]);
            split2(w1[0], w1[1], A1h.u[2], A1l.u[2]);
            split2(w1[2], w1[3], A1h.u[3], A1l.u[3]);
        } else {
            const unsigned short* xb = (const unsigned short*)x;
            A0h.s8 = *(const short8*)(xb + base);
            A1h.s8 = *(const short8*)(xb + base + 32);
            A0l.u[0] = A0l.u[1] = A0l.u[2] = A0l.u[3] = 0;
            A1l = A0l;
        }
        a0h = A0h.s8; a0l = A0l.s8; a1h = A1h.s8; a1l = A1l.s8;
    }
    __syncthreads();

#pragma unroll
    for (int m = 0; m < 3; m++) {
#pragma unroll
        for (int cb = 0; cb < 2; cb++) {
            int rowbase = (m * 32 + cb * 16 + l15) * 36;
            union { uint4 v; short8 s8; } B0h, B0l, B1h, B1l;
            B0h.v = *(const uint4*)&WTh[rowbase + Q * 4];
            B1h.v = *(const uint4*)&WTh[rowbase + 16 + Q * 4];
            B0l.v = *(const uint4*)&WTl[rowbase + Q * 4];
            B1l.v = *(const uint4*)&WTl[rowbase + 16 + Q * 4];
            f32x4 z = {0.f, 0.f, 0.f, 0.f};
            f32x4 acc = __builtin_amdgcn_mfma_f32_16x16x32_bf16(a0h, B0h.s8, z, 0, 0, 0);
            acc = __builtin_amdgcn_mfma_f32_16x16x32_bf16(a0h, B0l.s8, acc, 0, 0, 0);
            acc = __builtin_amdgcn_mfma_f32_16x16x32_bf16(a0l, B0h.s8, acc, 0, 0, 0);
            acc = __builtin_amdgcn_mfma_f32_16x16x32_bf16(a1h, B1h.s8, acc, 0, 0, 0);
            acc = __builtin_amdgcn_mfma_f32_16x16x32_bf16(a1h, B1l.s8, acc, 0, 0, 0);
            acc = __builtin_amdgcn_mfma_f32_16x16x32_bf16(a1l, B1h.s8, acc, 0, 0, 0);
            float bias = bL[m * 32 + cb * 16 + l15];
            if (m < 2) {
                unsigned short* dst = (m == 0) ? F : G;
#pragma unroll
                for (int r = 0; r < 4; r++)
                    dst[(row0 + Q * 4 + r) * 32 + cb * 16 + l15] = f2bf(acc[r] + bias);
            } else {
                int b = row0 >> 12;
                int n0 = (row0 & 4095) + Q * 4;
                uint2 pk;
                pk.x = pack2(acc[0] + bias, acc[1] + bias);
                pk.y = pack2(acc[2] + bias, acc[3] + bias);
                *(uint2*)(Ht + b * 131072 + (cb * 16 + l15) * 4096 + n0) = pk;
            }
        }
    }
}

// ---------------------------------------------------------------------------
// Kernel 2: flash attention (no-max exp2 on pre-scaled scores) + fused output
// projection.  256 WGs x 1024 thr (16 waves, K-split 16, 8 iters x 32 keys).
// LDS-free barrier-free K-loop with register double-buffer prefetch of next
// iteration's F/Ht fragments (breaks per-iter vmcnt serialization).
// ---------------------------------------------------------------------------
__global__ __launch_bounds__(1024, 4) void attn_kernel(
    const unsigned short* __restrict__ F, const unsigned short* __restrict__ G,
    const unsigned short* __restrict__ Ht,
    const void* __restrict__ x,
    const void* __restrict__ Wo, const void* __restrict__ bo,
    const void* __restrict__ gamma_p,
    void* __restrict__ out) {
    __shared__ float O_lds[16][32][32];
    __shared__ float l_lds[16][32];
    __shared__ float Om[32][33];
    __shared__ float lmg[32];
    __shared__ float WoL[32][64];
    __shared__ float boL[64];
    __shared__ int dflag;

    int tid = threadIdx.x;
    bool fp32 = detect_fp32(x, tid, &dflag);

    for (int i = tid; i < 2048; i += 1024) WoL[i >> 6][i & 63] = loadv(Wo, i, fp32);
    if (tid < 64) boL[tid] = loadv(bo, tid, fp32);

    int bx = blockIdx.x;            // 0..255
    int b = bx >> 7;                // batch
    int q0 = (bx & 127) << 5;       // 32 queries per WG
    int wave = tid >> 6;            // k-split index 0..15
    int lane = tid & 63;
    int Q = lane >> 4, l15 = lane & 15;

    const unsigned short* Fb = F + (b << 17);
    const unsigned short* Gb = G + (b << 17);
    const unsigned short* Htb = Ht + (b << 17);

    short8 g0 = *(const short8*)(Gb + ((q0 + l15) << 5) + (Q << 3));
    short8 g1 = *(const short8*)(Gb + ((q0 + 16 + l15) << 5) + (Q << 3));

    f32x4 O00 = {0.f, 0.f, 0.f, 0.f}, O01 = O00, O10 = O00, O11 = O00;
    float ls0 = 0.f, ls1 = 0.f;

    int k_begin = wave << 8;        // 256 keys per wave
    // prime prefetch with iteration 0
    short8 af0 = *(const short8*)(Fb + ((k_begin + l15) << 5) + (Q << 3));
    short8 af1 = *(const short8*)(Fb + ((k_begin + 16 + l15) << 5) + (Q << 3));
    short8 bh0 = *(const short8*)(Htb + (l15 << 12) + k_begin + (Q << 3));
    short8 bh1 = *(const short8*)(Htb + ((16 + l15) << 12) + k_begin + (Q << 3));

    for (int it = 0; it < 8; ++it) {
        // issue next iteration's loads before the compute chain
        int itn = (it < 7) ? it + 1 : 7;
        int kn = k_begin + (itn << 5);
        short8 naf0 = *(const short8*)(Fb + ((kn + l15) << 5) + (Q << 3));
        short8 naf1 = *(const short8*)(Fb + ((kn + 16 + l15) << 5) + (Q << 3));
        short8 nbh0 = *(const short8*)(Htb + (l15 << 12) + kn + (Q << 3));
        short8 nbh1 = *(const short8*)(Htb + ((16 + l15) << 12) + kn + (Q << 3));

        f32x4 z = {0.f, 0.f, 0.f, 0.f};
        f32x4 c00 = __builtin_amdgcn_mfma_f32_16x16x32_bf16(af0, g0, z, 0, 0, 0);
        f32x4 c01 = __builtin_amdgcn_mfma_f32_16x16x32_bf16(af1, g0, z, 0, 0, 0);
        f32x4 c10 = __builtin_amdgcn_mfma_f32_16x16x32_bf16(af0, g1, z, 0, 0, 0);
        f32x4 c11 = __builtin_amdgcn_mfma_f32_16x16x32_bf16(af1, g1, z, 0, 0, 0);

        // scores are pre-scaled by log2e (folded into Wg/bg) -> bare v_exp_f32
        float e00[4], e01[4], e10[4], e11[4];
#pragma unroll
        for (int r = 0; r < 4; r++) {
            e00[r] = __builtin_amdgcn_exp2f(c00[r]);
            e01[r] = __builtin_amdgcn_exp2f(c01[r]);
            e10[r] = __builtin_amdgcn_exp2f(c10[r]);
            e11[r] = __builtin_amdgcn_exp2f(c11[r]);
            ls0 += e00[r] + e01[r];
            ls1 += e10[r] + e11[r];
        }

        short8 pf0 = p_to_afrag(pack_trunc(e00[0], e00[1]), pack_trunc(e00[2], e00[3]),
                                pack_trunc(e01[0], e01[1]), pack_trunc(e01[2], e01[3]),
                                lane);
        short8 pf1 = p_to_afrag(pack_trunc(e10[0], e10[1]), pack_trunc(e10[2], e10[3]),
                                pack_trunc(e11[0], e11[1]), pack_trunc(e11[2], e11[3]),
                                lane);

        O00 = __builtin_amdgcn_mfma_f32_16x16x32_bf16(pf0, bh0, O00, 0, 0, 0);
        O01 = __builtin_amdgcn_mfma_f32_16x16x32_bf16(pf0, bh1, O01, 0, 0, 0);
        O10 = __builtin_amdgcn_mfma_f32_16x16x32_bf16(pf1, bh0, O10, 0, 0, 0);
        O11 = __builtin_amdgcn_mfma_f32_16x16x32_bf16(pf1, bh1, O11, 0, 0, 0);

        af0 = naf0; af1 = naf1; bh0 = nbh0; bh1 = nbh1;
    }

    ls0 += __shfl_xor(ls0, 16); ls0 += __shfl_xor(ls0, 32);
    ls1 += __shfl_xor(ls1, 16); ls1 += __shfl_xor(ls1, 32);
    if (Q == 0) {
        l_lds[wave][l15] = ls0;
        l_lds[wave][16 + l15] = ls1;
    }
#pragma unroll
    for (int r = 0; r < 4; r++) {
        O_lds[wave][(Q << 2) | r][l15]             = O00[r];
        O_lds[wave][(Q << 2) | r][16 + l15]        = O01[r];
        O_lds[wave][16 + ((Q << 2) | r)][l15]      = O10[r];
        O_lds[wave][16 + ((Q << 2) | r)][16 + l15] = O11[r];
    }
    __syncthreads();

    if (tid < 32) {
        float s = 0.f;
#pragma unroll
        for (int w = 0; w < 16; w++) s += l_lds[w][tid];
        lmg[tid] = 1.0f / s;
    }
    {
        int q = tid >> 5, c = tid & 31;
        float s = 0.f;
#pragma unroll
        for (int w = 0; w < 16; w++) s += O_lds[w][q][c];
        Om[q][c] = s;
    }
    __syncthreads();

    int q = tid >> 5;
    int ch = (tid & 31) << 1;
    float a0 = 0.f, a1 = 0.f;
#pragma unroll
    for (int c = 0; c < 32; c++) {
        float ob = Om[q][c];
        a0 += ob * WoL[c][ch];
        a1 += ob * WoL[c][ch + 1];
    }
    float inv = lmg[q];
    float gam = loadv(gamma_p, 0, fp32);
    int gq = q0 + q;
    int obase = (((b << 12) + gq) << 6) + ch;
    if (fp32) {
        float2 xv = *(const float2*)((const float*)x + obase);
        float2 ov;
        ov.x = xv.x + gam * (a0 * inv + boL[ch + 0]);
        ov.y = xv.y + gam * (a1 * inv + boL[ch + 1]);
        *(float2*)((float*)out + obase) = ov;
    } else {
        const unsigned short* xb = (const unsigned short*)x;
        unsigned short* ob16 = (unsigned short*)out;
        unsigned int pk = pack2(bf2f(xb[obase + 0]) + gam * (a0 * inv + boL[ch + 0]),
                                bf2f(xb[obase + 1]) + gam * (a1 * inv + boL[ch + 1]));
        *(unsigned int*)(ob16 + obase) = pk;
    }
}

extern "C" void kernel_launch(void* const* d_in, const int* in_sizes, int n_in,
                              void* d_out, int out_size, void* d_ws, size_t ws_size,
                              hipStream_t stream) {
    const void* x   = d_in[0];
    const void* Wf  = d_in[1];
    const void* bfv = d_in[2];
    const void* Wg  = d_in[3];
    const void* bgv = d_in[4];
    const void* Wh  = d_in[5];
    const void* bhv = d_in[6];
    const void* Wo  = d_in[7];
    const void* bo  = d_in[8];
    const void* gam = d_in[9];

    unsigned short* F  = (unsigned short*)d_ws;       // [B][N][32] bf16
    unsigned short* G  = F + 262144;                  // [B][N][32] bf16
    unsigned short* Ht = G + 262144;                  // [B][32][N] bf16

    proj_kernel<<<256, 128, 0, stream>>>(x, Wf, bfv, Wg, bgv, Wh, bhv, F, G, Ht);
    attn_kernel<<<256, 1024, 0, stream>>>(F, G, Ht, x, Wo, bo, gam, d_out);
}